// Round 1
// baseline (2091.914 us; speedup 1.0000x reference)
//
#include <hip/hip_runtime.h>
#include <math.h>

#define LOG0f (-1.0e30f)
#define ACTIVE_TH (-1.0e29f)
#define PRUNE_TH (-9.0f)
#define BW 8
#define VCAB 128
#define HSZ 4096
#define HMASK (HSZ - 1)
#define MAXT 256
#define MAXN (BW * MAXT + 1)
#define HEMPTY 0xFFFFFFFFu

// JAX-exact logaddexp: max + log1p(exp(-|a-b|)) in f32
__device__ __forceinline__ float lae(float a, float b) {
    float mx = fmaxf(a, b);
    float d = fabsf(a - b);
    return mx + log1pf(expf(-d));
}

// monotonic float->uint transform (order-preserving)
__device__ __forceinline__ unsigned mono(float f) {
    unsigned u = __float_as_uint(f);
    return (u & 0x80000000u) ? ~u : (u | 0x80000000u);
}
__device__ __forceinline__ float mono_inv(unsigned m) {
    unsigned u = (m & 0x80000000u) ? (m & 0x7FFFFFFFu) : ~m;
    return __uint_as_float(u);
}

__global__ __launch_bounds__(64)
void ctc_beam_kernel(const float* __restrict__ probs, const int* __restrict__ lengths,
                     const int* __restrict__ blank_p, int* __restrict__ out_seq,
                     int* __restrict__ out_len, int T) {
    // persistent prefix trie: node 0 = root (empty prefix)
    __shared__ unsigned hsh[HSZ];            // dedup map (parent,label)->node: (key<<12)|id
    __shared__ unsigned short nparent[MAXN];
    __shared__ unsigned char nlabel[MAXN];
    __shared__ float sh_pr[VCAB];
    __shared__ float bm_pb[BW], bm_pnb[BW], bm_ptot[BW], bm_contb[BW], bm_contnb[BW];
    __shared__ int bm_len[BW];
    __shared__ unsigned short bm_node[BW];
    __shared__ int bm_last[BW];
    __shared__ int bm_act[BW];
    __shared__ unsigned childmask[BW * 4];   // 128 bits per beam
    __shared__ int node_cnt;
    __shared__ int sh_seq[MAXT];

    const int lane = threadIdx.x;
    const int b = blockIdx.x;
    const int blank = blank_p[0];
    const int length = lengths[b];
    const float* __restrict__ P = probs + (size_t)b * T * VCAB;

    for (int i = lane; i < HSZ; i += 64) hsh[i] = HEMPTY;
    if (lane < BW) {
        bm_node[lane] = 0;
        bm_len[lane] = 0;
        bm_pb[lane] = (lane == 0) ? 0.0f : LOG0f;  // root: blank prob = log(1)
        bm_pnb[lane] = LOG0f;
    }
    if (lane == 0) { node_cnt = 1; nparent[0] = 0xFFFF; nlabel[0] = 0; }
    __syncthreads();

    // software-pipelined log-prob loads: lane owns labels {lane, lane+64}
    float prL = P[lane];
    float prH = P[64 + lane];

    for (int t = 0; t < length; ++t) {
        sh_pr[lane] = prL;
        sh_pr[lane + 64] = prH;
        if (lane < BW * 4) childmask[lane] = 0;
        float nprL = 0.f, nprH = 0.f;
        if (t + 1 < length) {
            nprL = P[(size_t)(t + 1) * VCAB + lane];
            nprH = P[(size_t)(t + 1) * VCAB + 64 + lane];
        }
        __syncthreads();

        const float prB = sh_pr[blank];

        // phase 1: per-beam totals / act / last
        if (lane < BW) {
            float pb = bm_pb[lane], pnb = bm_pnb[lane];
            float pt = lae(pb, pnb);
            bm_ptot[lane] = pt;
            bm_act[lane] = (pt > ACTIVE_TH) ? 1 : 0;
            int len = bm_len[lane];
            bm_last[lane] = (len > 0) ? (int)nlabel[bm_node[lane]] : blank;
        }
        __syncthreads();

        // phase 2: parent match (by trie-node identity), branch updates, child_in marks
        if (lane < BW) {
            const int i = lane;
            const int len = bm_len[i];
            const int act = bm_act[i];
            const int last = bm_last[i];
            float par_prev = LOG0f;
            int par = -1;
            if (act && len > 0) {
                unsigned short pn = nparent[bm_node[i]];
                for (int j = 0; j < BW; ++j) {
                    if (j != i && bm_act[j] && bm_node[j] == pn && bm_len[j] == len - 1) {
                        par = j;
                        break;
                    }
                }
            }
            if (par >= 0) {
                par_prev = (last == bm_last[par]) ? bm_pb[par] : bm_ptot[par];
                atomicOr(&childmask[par * 4 + (last >> 5)], 1u << (last & 31));
            }
            bm_contb[i] = bm_ptot[i] + prB;
            bm_contnb[i] = (len > 0) ? (lae(bm_pnb[i], par_prev) + sh_pr[last]) : LOG0f;
        }
        __syncthreads();

        // phase 3: build 17 candidate keys per lane
        //   ref index space: [0..7]=continuations, [8..8+1024)=extensions i*V+v
        unsigned long long key[17];
        #pragma unroll
        for (int k = 0; k < 16; ++k) {
            const int i = k >> 1;
            const int v = (k & 1) ? (lane + 64) : lane;
            const float pv = (k & 1) ? prH : prL;
            float prev = (v == bm_last[i]) ? bm_pb[i] : bm_ptot[i];
            float val = pv + prev;
            bool bad = (v == blank) || (pv <= PRUNE_TH) || (!bm_act[i]) ||
                       ((childmask[i * 4 + (v >> 5)] >> (v & 31)) & 1u);
            if (bad) val = LOG0f;
            unsigned refidx = 8u + (unsigned)(i * VCAB + v);
            key[k] = ((unsigned long long)mono(val) << 32) | (unsigned)(~refidx);
        }
        if (lane < BW) {
            float tot = lae(bm_contb[lane], bm_contnb[lane]);
            key[16] = ((unsigned long long)mono(tot) << 32) | (unsigned)(~(unsigned)lane);
        } else {
            key[16] = 0ull;
        }

        // phase 4: top-8 by repeated wave-max (lazy per-lane rescan)
        unsigned long long loc = 0ull;
        #pragma unroll
        for (int k = 0; k < 17; ++k) loc = (key[k] > loc) ? key[k] : loc;

        unsigned my_sel = 0;
        float my_val = 0.f;
        for (int r = 0; r < BW; ++r) {
            unsigned long long best = loc;
            #pragma unroll
            for (int m = 32; m >= 1; m >>= 1) {
                unsigned long long o = __shfl_xor(best, m, 64);
                best = (o > best) ? o : best;
            }
            if (lane == r) {
                my_sel = ~(unsigned)(best & 0xFFFFFFFFull);
                my_val = mono_inv((unsigned)(best >> 32));
            }
            if (loc == best) {  // this lane owned the winner: remove & rescan
                #pragma unroll
                for (int k = 0; k < 17; ++k)
                    if (key[k] == best) key[k] = 0ull;
                loc = 0ull;
                #pragma unroll
                for (int k = 0; k < 17; ++k) loc = (key[k] > loc) ? key[k] : loc;
            }
        }

        // phase 5: compute new beam states (into regs), then publish
        float npb = 0.f, npnb = 0.f;
        int nlen = 0;
        unsigned short nnode = 0;
        if (lane < BW) {
            if (my_sel < BW) {  // continuation
                int s = (int)my_sel;
                nnode = bm_node[s];
                nlen = bm_len[s];
                npb = bm_contb[s];
                npnb = bm_contnb[s];
            } else {  // extension: (src beam s, label lab); total==ext_nb bitwise
                unsigned e = my_sel - BW;
                int s = (int)(e >> 7);
                int lab = (int)(e & 127u);
                npb = LOG0f;
                npnb = my_val;
                nlen = bm_len[s] + 1;
                unsigned short cs = bm_node[s];
                unsigned hkey = (((unsigned)cs) << 7) | (unsigned)lab;
                int id = atomicAdd(&node_cnt, 1);  // speculative; bounded by 8*T
                unsigned entry = (hkey << 12) | (unsigned)id;
                unsigned h = (hkey * 2654435761u) >> 20;
                h &= HMASK;
                for (;;) {
                    unsigned prev = atomicCAS(&hsh[h], HEMPTY, entry);
                    if (prev == HEMPTY) {
                        nparent[id] = cs;
                        nlabel[id] = (unsigned char)lab;
                        nnode = (unsigned short)id;
                        break;
                    }
                    if ((prev >> 12) == hkey) {  // dedup hit: reuse content node
                        nnode = (unsigned short)(prev & 0xFFFu);
                        break;
                    }
                    h = (h + 1) & HMASK;
                }
            }
        }
        __syncthreads();
        if (lane < BW) {
            bm_pb[lane] = npb;
            bm_pnb[lane] = npnb;
            bm_len[lane] = nlen;
            bm_node[lane] = nnode;
        }
        __syncthreads();

        prL = nprL;
        prH = nprH;
    }

    // final: argmax of totals (first max), reconstruct via parent walk
    unsigned long long fk = 0ull;
    if (lane < BW)
        fk = ((unsigned long long)mono(lae(bm_pb[lane], bm_pnb[lane])) << 32) |
             (unsigned)(~(unsigned)lane);
    #pragma unroll
    for (int m = 32; m >= 1; m >>= 1) {
        unsigned long long o = __shfl_xor(fk, m, 64);
        fk = (o > fk) ? o : fk;
    }
    const int best = (int)(~(unsigned)(fk & 0xFFFFFFFFull));
    const int L = bm_len[best];
    if (lane == 0) {
        unsigned short c = bm_node[best];
        for (int k = L - 1; k >= 0; --k) {
            sh_seq[k] = (int)nlabel[c];
            c = nparent[c];
        }
    }
    __syncthreads();
    for (int j = lane; j < T; j += 64)
        out_seq[(size_t)b * T + j] = (j < L) ? sh_seq[j] : 0;
    if (lane == 0) out_len[b] = L;
}

extern "C" void kernel_launch(void* const* d_in, const int* in_sizes, int n_in,
                              void* d_out, int out_size, void* d_ws, size_t ws_size,
                              hipStream_t stream) {
    const float* probs = (const float*)d_in[0];
    const int* lengths = (const int*)d_in[1];
    // d_in[2] = beam_width (fixed 8, compiled in); d_in[3] = blank_index
    const int* blank_p = (const int*)d_in[3];
    const int B = in_sizes[1];
    const int T = in_sizes[0] / (B * VCAB);
    int* out = (int*)d_out;
    ctc_beam_kernel<<<B, 64, 0, stream>>>(probs, lengths, blank_p, out,
                                          out + (size_t)B * T, T);
}